// Round 1
// baseline (12185.951 us; speedup 1.0000x reference)
//
#include <hip/hip_runtime.h>
#include <hip/hip_bf16.h>
#include <stdint.h>

// LSTM: T=512, B=64, F=256, H=1024, CLASSES=1000
// Strategy: persistent cooperative kernel, 256 WGs (1/CU), W slice in LDS,
// bf16 MFMA 16x16x32, x-projection folded into K (K=1280), h exchanged via
// double-buffered global bf16 buffer + monotone atomic grid barrier.

typedef __bf16 bf16;
typedef __bf16 bf16x8 __attribute__((ext_vector_type(8)));
typedef __bf16 bf16x4 __attribute__((ext_vector_type(4)));
typedef float  f32x4  __attribute__((ext_vector_type(4)));

#define NWG     256
#define TSTEPS  512
#define BATCH   64
#define FEAT    256
#define HID     1024
#define KTOT    1280   // HID + FEAT
#define WPITCH  1288   // +8 bf16 pad -> bank-conflict-free ds_read_b128

// d_ws byte offsets (total ~27.6 MB)
#define WS_X   ((size_t)0)                 // bf16 x [512][64][256]   16,777,216 B
#define WS_W   ((size_t)16777216)          // bf16 Wcomb [4096][1280] 10,485,760 B
#define WS_H0  (WS_W + (size_t)10485760)   // bf16 h buf0 [64][1024]     131,072 B
#define WS_H1  (WS_H0 + (size_t)131072)    // bf16 h buf1
#define WS_CNT (WS_H1 + (size_t)131072)    // unsigned barrier counter

__global__ void k_zero(bf16* __restrict__ hbufs, unsigned* __restrict__ cnt) {
  size_t i = (size_t)blockIdx.x * blockDim.x + threadIdx.x;  // 16384 threads x 16B
  ((uint4*)hbufs)[i] = make_uint4(0u, 0u, 0u, 0u);
  if (i == 0) *cnt = 0u;
}

__global__ void k_conv_x(const float* __restrict__ x, bf16* __restrict__ xb) {
  size_t i = ((size_t)blockIdx.x * blockDim.x + threadIdx.x) * 4;
  float4 v = *(const float4*)(x + i);
  bf16x4 o = { (bf16)v.x, (bf16)v.y, (bf16)v.z, (bf16)v.w };
  *(bf16x4*)(xb + i) = o;
}

// Wcomb row r (= gate*1024 + hcol): k<1024 -> W_hh[r][k];  k>=1024 -> W_ih[r][k-1024]
__global__ void k_build_w(const float* __restrict__ Wih, const float* __restrict__ Whh,
                          bf16* __restrict__ Wc) {
  int r = blockIdx.x;
  int k4;
  const float* src;
  if (blockIdx.y == 0) {
    k4 = threadIdx.x * 4;                       // 0..1020
    src = Whh + (size_t)r * HID + k4;
  } else {
    if (threadIdx.x >= 64) return;              // x-part: 256 cols
    k4 = 1024 + threadIdx.x * 4;
    src = Wih + (size_t)r * FEAT + threadIdx.x * 4;
  }
  float4 v = *(const float4*)src;
  bf16x4 o = { (bf16)v.x, (bf16)v.y, (bf16)v.z, (bf16)v.w };
  *(bf16x4*)(Wc + (size_t)r * KTOT + k4) = o;
}

__device__ __forceinline__ float sigm(float x) { return 1.f / (1.f + __expf(-x)); }
__device__ __forceinline__ float tanh_fast(float x) { return 2.f / (1.f + __expf(-2.f * x)) - 1.f; }

__global__ __launch_bounds__(256, 1) void k_lstm(
    const float* __restrict__ bih, const float* __restrict__ bhh,
    const bf16* __restrict__ xb, const bf16* __restrict__ Wc,
    bf16* __restrict__ h0, bf16* __restrict__ h1, unsigned* __restrict__ cnt)
{
  __shared__ bf16  Wl[32 * WPITCH];   // 82,432 B: WG's 32 gate rows x K=1280 (+pad)
  __shared__ float gl[32][33];        // gates staging, +1 pad col
  __shared__ bf16  hstage[32][8];

  const int tid = threadIdx.x;
  const int wg  = blockIdx.x;
  const int ib  = wg & 1;      // batch half (32 rows)
  const int j   = wg >> 1;     // h block (8 h-cols), 0..127

  // ---- load weight slice into LDS (rows n = g*8+u -> global row g*1024 + j*8 + u)
  {
    const int n = tid >> 3;                       // 0..31
    const int g = n >> 3, u = n & 7;
    const bf16* srow = Wc + (size_t)(g * 1024 + j * 8 + u) * KTOT;
    bf16* drow = Wl + n * WPITCH;
    const int c0 = (tid & 7) * 8;
#pragma unroll
    for (int it = 0; it < 20; ++it) {
      int e = c0 + it * 64;                       // covers 0..1279
      *(bf16x8*)(drow + e) = *(const bf16x8*)(srow + e);
    }
  }

  const int lane = tid & 63;
  const int wv   = tid >> 6;         // 4 waves
  const int mt   = wv & 1;           // M-tile (16 batches)
  const int nt   = wv >> 1;          // N-tile (16 gate cols)
  const int ln   = lane & 15;
  const int hg   = lane >> 4;        // 0..3

  float bias_r;                      // per-lane: bias of gate col (nt*16+ln)
  {
    int nl = nt * 16 + ln;
    int g = nl >> 3, u = nl & 7;
    int r = g * 1024 + j * 8 + u;
    bias_r = bih[r] + bhh[r];
  }

  const int eb = tid & 31, eu = tid >> 5;   // epilogue ownership: (batch eb, hcol eu)
  float c_st = 0.f;                         // cell state, fp32 in register

  const int bg = ib * 32 + mt * 16 + ln;    // global batch row for A fragment
  const bf16* brow = Wl + (nt * 16 + ln) * WPITCH + hg * 8;

  __syncthreads();

  for (int t = 0; t < TSTEPS; ++t) {
    const bf16* hc = (t & 1) ? h1 : h0;     // read h_{t-1}
    bf16*       hn = (t & 1) ? h0 : h1;     // write h_t

    f32x4 acc = {0.f, 0.f, 0.f, 0.f};
    const bf16* ah = hc + (size_t)bg * HID + hg * 8;
    const bf16* ax = xb + (size_t)t * (BATCH * FEAT) + (size_t)bg * FEAT + hg * 8;
#pragma unroll
    for (int kc = 0; kc < 32; ++kc) {       // h part: K = 0..1023
      bf16x8 a = *(const bf16x8*)(ah + kc * 32);
      bf16x8 b = *(const bf16x8*)(brow + kc * 32);
      acc = __builtin_amdgcn_mfma_f32_16x16x32_bf16(a, b, acc, 0, 0, 0);
    }
#pragma unroll
    for (int kc = 0; kc < 8; ++kc) {        // x part: K = 1024..1279
      bf16x8 a = *(const bf16x8*)(ax + kc * 32);
      bf16x8 b = *(const bf16x8*)(brow + 1024 + kc * 32);
      acc = __builtin_amdgcn_mfma_f32_16x16x32_bf16(a, b, acc, 0, 0, 0);
    }

    // C/D layout (verified): col = lane&15, row = (lane>>4)*4 + reg
#pragma unroll
    for (int r = 0; r < 4; ++r)
      gl[mt * 16 + hg * 4 + r][nt * 16 + ln] = acc[r] + bias_r;
    __syncthreads();

    // ---- LSTM cell (each thread owns one (batch, hcol))
    float gi = gl[eb][ 0 + eu];
    float gf = gl[eb][ 8 + eu];
    float gc = gl[eb][16 + eu];
    float go = gl[eb][24 + eu];
    gi = sigm(gi); gf = sigm(gf); go = sigm(go); gc = tanh_fast(gc);
    c_st = gf * c_st + gi * gc;
    hstage[eb][eu] = (bf16)(go * tanh_fast(c_st));
    __syncthreads();

    if (tid < 32) {   // coalesced 16B h writes: rows ib*32+tid, cols [j*8, j*8+8)
      bf16x8 v = *(const bf16x8*)&hstage[tid][0];
      *(bf16x8*)(hn + (size_t)(ib * 32 + tid) * HID + j * 8) = v;
    }
    __syncthreads();  // drains vmcnt for the storing wave before the fence

    // ---- grid barrier (monotone counter, agent-scope release/acquire)
    if (tid == 0) {
      __threadfence();                       // release: L2 writeback to LLC
      atomicAdd(cnt, 1u);
      const unsigned target = (unsigned)NWG * (unsigned)(t + 1);
      while (__hip_atomic_load(cnt, __ATOMIC_RELAXED, __HIP_MEMORY_SCOPE_AGENT) < target)
        __builtin_amdgcn_s_sleep(1);
      __threadfence();                       // acquire: invalidate L1/L2
    }
    __syncthreads();
  }
}

// out[b][c] = sum_k h_last[b][k] * Wfc[c][k]   (131 MFLOP, L2-resident)
__global__ __launch_bounds__(256) void k_fc(const bf16* __restrict__ h,
                                            const float* __restrict__ Wfc,
                                            float* __restrict__ out) {
  const int tid = threadIdx.x;
  const int ci = tid & 3, b = tid >> 2;
  const int c = blockIdx.x * 4 + ci;
  const bf16*  hr = h   + (size_t)b * HID;
  const float* wr = Wfc + (size_t)c * HID;
  float acc = 0.f;
#pragma unroll 4
  for (int k8 = 0; k8 < 128; ++k8) {
    bf16x8 hv = *(const bf16x8*)(hr + k8 * 8);
    f32x4  w0 = *(const f32x4*)(wr + k8 * 8);
    f32x4  w1 = *(const f32x4*)(wr + k8 * 8 + 4);
    acc += (float)hv[0] * w0[0] + (float)hv[1] * w0[1] + (float)hv[2] * w0[2] + (float)hv[3] * w0[3]
         + (float)hv[4] * w1[0] + (float)hv[5] * w1[1] + (float)hv[6] * w1[2] + (float)hv[7] * w1[3];
  }
  out[(size_t)b * 1000 + c] = acc;
}

extern "C" void kernel_launch(void* const* d_in, const int* in_sizes, int n_in,
                              void* d_out, int out_size, void* d_ws, size_t ws_size,
                              hipStream_t stream) {
  (void)in_sizes; (void)n_in; (void)out_size; (void)ws_size;
  const float* x   = (const float*)d_in[0];
  const float* Wih = (const float*)d_in[1];
  const float* Whh = (const float*)d_in[2];
  const float* bih = (const float*)d_in[3];
  const float* bhh = (const float*)d_in[4];
  const float* Wfc = (const float*)d_in[5];
  char* ws = (char*)d_ws;
  bf16* xb = (bf16*)(ws + WS_X);
  bf16* Wc = (bf16*)(ws + WS_W);
  bf16* h0 = (bf16*)(ws + WS_H0);
  bf16* h1 = (bf16*)(ws + WS_H1);
  unsigned* cnt = (unsigned*)(ws + WS_CNT);

  hipLaunchKernelGGL(k_zero,    dim3(64),      dim3(256), 0, stream, h0, cnt);
  hipLaunchKernelGGL(k_conv_x,  dim3(8192),    dim3(256), 0, stream, x, xb);
  hipLaunchKernelGGL(k_build_w, dim3(4096, 2), dim3(256), 0, stream, Wih, Whh, Wc);
  hipLaunchKernelGGL(k_lstm,    dim3(NWG),     dim3(256), 0, stream, bih, bhh, xb, Wc, h0, h1, cnt);
  hipLaunchKernelGGL(k_fc,      dim3(250),     dim3(256), 0, stream, h0, Wfc, (float*)d_out);
}

// Round 5
// 8855.720 us; speedup vs baseline: 1.3761x; 1.3761x over previous
//
#include <hip/hip_runtime.h>
#include <hip/hip_bf16.h>
#include <stdint.h>

// LSTM T=512 B=64 F=256 H=1024 CLASSES=1000 — persistent kernel, 256 WGs.
// Round 5: round-1 kernel VERBATIM (proven correct, 12.2ms) with exactly ONE
// change: the serialized 256-way atomicAdd counter barrier (measured ~23.8
// us/step) is replaced by a contention-free per-WG flag array:
//   publish: atomicExch(ownflag, t+1)  (parallel RMWs, private 64B lines)
//   wait:    thread i polls flag i (256 flags, 1 load round-trip, global wait)
// Fences are round-1's exact __threadfence pair, same thread, same position.

typedef __bf16 bf16;
typedef __bf16 bf16x8 __attribute__((ext_vector_type(8)));
typedef __bf16 bf16x4 __attribute__((ext_vector_type(4)));
typedef float  f32x4  __attribute__((ext_vector_type(4)));

#define NWG     256
#define TSTEPS  512
#define BATCH   64
#define FEAT    256
#define HID     1024
#define KTOT    1280
#define WPITCH  1288   // +8 bf16 pad -> conflict-free ds_read_b128

// d_ws layout
#define WS_X    ((size_t)0)                  // bf16 x [512][64][256]  16,777,216 B
#define WS_W    ((size_t)16777216)           // bf16 Wcomb [4096][1280] 10,485,760 B
#define WS_H0   (WS_W + (size_t)10485760)    // bf16 h0 [64][1024]  131,072 B
#define WS_H1   (WS_H0 + (size_t)131072)     // bf16 h1
#define WS_FLG  (WS_H1 + (size_t)131072)     // 256 flags, 64B stride = 16,384 B

__global__ void k_zero(uint4* __restrict__ p) {
  size_t i = (size_t)blockIdx.x * blockDim.x + threadIdx.x;  // 68*256*16B = 278,528 B
  p[i] = make_uint4(0u, 0u, 0u, 0u);
}

__global__ void k_conv_x(const float* __restrict__ x, bf16* __restrict__ xb) {
  size_t i = ((size_t)blockIdx.x * blockDim.x + threadIdx.x) * 4;
  float4 v = *(const float4*)(x + i);
  bf16x4 o = { (bf16)v.x, (bf16)v.y, (bf16)v.z, (bf16)v.w };
  *(bf16x4*)(xb + i) = o;
}

__global__ void k_build_w(const float* __restrict__ Wih, const float* __restrict__ Whh,
                          bf16* __restrict__ Wc) {
  int r = blockIdx.x;
  int k4;
  const float* src;
  if (blockIdx.y == 0) {
    k4 = threadIdx.x * 4;
    src = Whh + (size_t)r * HID + k4;
  } else {
    if (threadIdx.x >= 64) return;
    k4 = 1024 + threadIdx.x * 4;
    src = Wih + (size_t)r * FEAT + threadIdx.x * 4;
  }
  float4 v = *(const float4*)src;
  bf16x4 o = { (bf16)v.x, (bf16)v.y, (bf16)v.z, (bf16)v.w };
  *(bf16x4*)(Wc + (size_t)r * KTOT + k4) = o;
}

__device__ __forceinline__ float sigm(float x) { return 1.f / (1.f + __expf(-x)); }
__device__ __forceinline__ float tanh_fast(float x) { return 2.f / (1.f + __expf(-2.f * x)) - 1.f; }

__global__ __launch_bounds__(256, 1) void k_lstm(
    const float* __restrict__ bih, const float* __restrict__ bhh,
    const bf16* __restrict__ xb, const bf16* __restrict__ Wc,
    bf16* __restrict__ h0, bf16* __restrict__ h1, unsigned* __restrict__ flags)
{
  __shared__ bf16  Wl[32 * WPITCH];   // 82,432 B
  __shared__ float gl[32][33];        // gates staging, +1 pad col
  __shared__ bf16  hstage[32][8];

  const int tid = threadIdx.x;
  const int wg  = blockIdx.x;
  const int ib  = wg & 1;      // batch half (32 rows)
  const int j   = wg >> 1;     // h block (8 h-cols), 0..127

  // ---- load weight slice into LDS (rows n = g*8+u -> global row g*1024 + j*8 + u)
  {
    const int n = tid >> 3;                       // 0..31
    const int g = n >> 3, u = n & 7;
    const bf16* srow = Wc + (size_t)(g * 1024 + j * 8 + u) * KTOT;
    bf16* drow = Wl + n * WPITCH;
    const int c0 = (tid & 7) * 8;
#pragma unroll
    for (int it = 0; it < 20; ++it) {
      int e = c0 + it * 64;                       // covers 0..1279
      *(bf16x8*)(drow + e) = *(const bf16x8*)(srow + e);
    }
  }

  const int lane = tid & 63;
  const int wv   = tid >> 6;         // 4 waves
  const int mt   = wv & 1;           // M-tile (16 batches)
  const int nt   = wv >> 1;          // N-tile (16 gate cols)
  const int ln   = lane & 15;
  const int hg   = lane >> 4;        // 0..3

  float bias_r;                      // per-lane: bias of gate col (nt*16+ln)
  {
    int nl = nt * 16 + ln;
    int g = nl >> 3, u = nl & 7;
    int r = g * 1024 + j * 8 + u;
    bias_r = bih[r] + bhh[r];
  }

  const int eb = tid & 31, eu = tid >> 5;   // epilogue ownership: (batch eb, hcol eu)
  float c_st = 0.f;                         // cell state, fp32 in register

  const int bg = ib * 32 + mt * 16 + ln;    // global batch row for A fragment
  const bf16* brow = Wl + (nt * 16 + ln) * WPITCH + hg * 8;

  unsigned* pollflag = flags + (size_t)tid * 16;   // thread i polls WG i's flag
  unsigned* ownflag  = flags + (size_t)wg  * 16;

  __syncthreads();

  for (int t = 0; t < TSTEPS; ++t) {
    const bf16* hc = (t & 1) ? h1 : h0;     // read h_{t-1}
    bf16*       hn = (t & 1) ? h0 : h1;     // write h_t

    // ---- grid barrier wait: thread i polls WG i's flag (contention-free)
    if (t) {
      while (__hip_atomic_load(pollflag, __ATOMIC_RELAXED, __HIP_MEMORY_SCOPE_AGENT) < (unsigned)t)
        __builtin_amdgcn_s_sleep(1);
      if (tid == 0) __threadfence();         // acquire: invalidate L1/L2
    }
    __syncthreads();

    f32x4 acc = {0.f, 0.f, 0.f, 0.f};
    const bf16* ah = hc + (size_t)bg * HID + hg * 8;
    const bf16* ax = xb + (size_t)t * (BATCH * FEAT) + (size_t)bg * FEAT + hg * 8;
#pragma unroll
    for (int kc = 0; kc < 32; ++kc) {       // h part: K = 0..1023
      bf16x8 a = *(const bf16x8*)(ah + kc * 32);
      bf16x8 b = *(const bf16x8*)(brow + kc * 32);
      acc = __builtin_amdgcn_mfma_f32_16x16x32_bf16(a, b, acc, 0, 0, 0);
    }
#pragma unroll
    for (int kc = 0; kc < 8; ++kc) {        // x part: K = 1024..1279
      bf16x8 a = *(const bf16x8*)(ax + kc * 32);
      bf16x8 b = *(const bf16x8*)(brow + 1024 + kc * 32);
      acc = __builtin_amdgcn_mfma_f32_16x16x32_bf16(a, b, acc, 0, 0, 0);
    }

    // C/D layout (verified): col = lane&15, row = (lane>>4)*4 + reg
#pragma unroll
    for (int r = 0; r < 4; ++r)
      gl[mt * 16 + hg * 4 + r][nt * 16 + ln] = acc[r] + bias_r;
    __syncthreads();

    // ---- LSTM cell (each thread owns one (batch, hcol))
    float gi = gl[eb][ 0 + eu];
    float gf = gl[eb][ 8 + eu];
    float gc = gl[eb][16 + eu];
    float go = gl[eb][24 + eu];
    gi = sigm(gi); gf = sigm(gf); go = sigm(go); gc = tanh_fast(gc);
    c_st = gf * c_st + gi * gc;
    hstage[eb][eu] = (bf16)(go * tanh_fast(c_st));
    __syncthreads();

    if (tid < 32) {   // coalesced 16B h writes: rows ib*32+tid, cols [j*8, j*8+8)
      bf16x8 v = *(const bf16x8*)&hstage[tid][0];
      *(bf16x8*)(hn + (size_t)(ib * 32 + tid) * HID + j * 8) = v;
    }
    __syncthreads();  // storing wave reaches fence below with stores issued

    // ---- publish: release fence (round-1 exact) + contention-free flag RMW
    if (tid == 0) {
      __threadfence();                       // release: L2 writeback
      atomicExch(ownflag, (unsigned)(t + 1));
    }
  }
}

// out[b][c] = sum_k h_last[b][k] * Wfc[c][k]   (131 MFLOP, L2-resident)
__global__ __launch_bounds__(256) void k_fc(const bf16* __restrict__ h,
                                            const float* __restrict__ Wfc,
                                            float* __restrict__ out) {
  const int tid = threadIdx.x;
  const int ci = tid & 3, b = tid >> 2;
  const int c = blockIdx.x * 4 + ci;
  const bf16*  hr = h   + (size_t)b * HID;
  const float* wr = Wfc + (size_t)c * HID;
  float acc = 0.f;
#pragma unroll 4
  for (int k8 = 0; k8 < 128; ++k8) {
    bf16x8 hv = *(const bf16x8*)(hr + k8 * 8);
    f32x4  w0 = *(const f32x4*)(wr + k8 * 8);
    f32x4  w1 = *(const f32x4*)(wr + k8 * 8 + 4);
    acc += (float)hv[0] * w0[0] + (float)hv[1] * w0[1] + (float)hv[2] * w0[2] + (float)hv[3] * w0[3]
         + (float)hv[4] * w1[0] + (float)hv[5] * w1[1] + (float)hv[6] * w1[2] + (float)hv[7] * w1[3];
  }
  out[(size_t)b * 1000 + c] = acc;
}

extern "C" void kernel_launch(void* const* d_in, const int* in_sizes, int n_in,
                              void* d_out, int out_size, void* d_ws, size_t ws_size,
                              hipStream_t stream) {
  (void)in_sizes; (void)n_in; (void)out_size; (void)ws_size;
  const float* x   = (const float*)d_in[0];
  const float* Wih = (const float*)d_in[1];
  const float* Whh = (const float*)d_in[2];
  const float* bih = (const float*)d_in[3];
  const float* bhh = (const float*)d_in[4];
  const float* Wfc = (const float*)d_in[5];
  char* ws = (char*)d_ws;
  bf16* xb = (bf16*)(ws + WS_X);
  bf16* Wc = (bf16*)(ws + WS_W);
  bf16* h0 = (bf16*)(ws + WS_H0);
  bf16* h1 = (bf16*)(ws + WS_H1);
  unsigned* flags = (unsigned*)(ws + WS_FLG);

  hipLaunchKernelGGL(k_zero,    dim3(68),      dim3(256), 0, stream, (uint4*)(ws + WS_H0));
  hipLaunchKernelGGL(k_conv_x,  dim3(8192),    dim3(256), 0, stream, x, xb);
  hipLaunchKernelGGL(k_build_w, dim3(4096, 2), dim3(256), 0, stream, Wih, Whh, Wc);
  hipLaunchKernelGGL(k_lstm,    dim3(NWG),     dim3(256), 0, stream, bih, bhh, xb, Wc, h0, h1, flags);
  hipLaunchKernelGGL(k_fc,      dim3(250),     dim3(256), 0, stream, h0, Wfc, (float*)d_out);
}

// Round 6
// 5209.686 us; speedup vs baseline: 2.3391x; 1.6999x over previous
//
#include <hip/hip_runtime.h>
#include <hip/hip_bf16.h>
#include <stdint.h>

// LSTM T=512 B=64 F=256 H=1024 CLASSES=1000 — persistent kernel, 256 WGs.
// Round 6: round-5 compute VERBATIM; coherence reworked to fence-free:
//   - h reads:  agent-scope atomic u64 loads (proven-fresh: round-5 poll)
//   - h writes: atomicExch u64 (return kept live) + s_waitcnt vmcnt(0)
//   - no __threadfence anywhere in the loop (no buffer_wbl2 / buffer_inv)
//   - poll: 64 threads x 4 flags (same global wait set), s_sleep backoff
//   - x-projection MFMA hoisted above the poll (xb immutable)

typedef __bf16 bf16;
typedef __bf16 bf16x8 __attribute__((ext_vector_type(8)));
typedef __bf16 bf16x4 __attribute__((ext_vector_type(4)));
typedef float  f32x4  __attribute__((ext_vector_type(4)));
typedef unsigned long long u64;

#define NWG     256
#define TSTEPS  512
#define BATCH   64
#define FEAT    256
#define HID     1024
#define KTOT    1280
#define WPITCH  1288   // +8 bf16 pad -> conflict-free ds_read_b128

// d_ws layout
#define WS_X    ((size_t)0)                  // bf16 x [512][64][256]  16,777,216 B
#define WS_W    ((size_t)16777216)           // bf16 Wcomb [4096][1280] 10,485,760 B
#define WS_H0   (WS_W + (size_t)10485760)    // bf16 h0 [64][1024]  131,072 B
#define WS_H1   (WS_H0 + (size_t)131072)     // bf16 h1
#define WS_FLG  (WS_H1 + (size_t)131072)     // 256 flags, 64B stride = 16,384 B

__global__ void k_zero(uint4* __restrict__ p) {
  size_t i = (size_t)blockIdx.x * blockDim.x + threadIdx.x;  // 68*256*16B = 278,528 B
  p[i] = make_uint4(0u, 0u, 0u, 0u);
}

__global__ void k_conv_x(const float* __restrict__ x, bf16* __restrict__ xb) {
  size_t i = ((size_t)blockIdx.x * blockDim.x + threadIdx.x) * 4;
  float4 v = *(const float4*)(x + i);
  bf16x4 o = { (bf16)v.x, (bf16)v.y, (bf16)v.z, (bf16)v.w };
  *(bf16x4*)(xb + i) = o;
}

__global__ void k_build_w(const float* __restrict__ Wih, const float* __restrict__ Whh,
                          bf16* __restrict__ Wc) {
  int r = blockIdx.x;
  int k4;
  const float* src;
  if (blockIdx.y == 0) {
    k4 = threadIdx.x * 4;
    src = Whh + (size_t)r * HID + k4;
  } else {
    if (threadIdx.x >= 64) return;
    k4 = 1024 + threadIdx.x * 4;
    src = Wih + (size_t)r * FEAT + threadIdx.x * 4;
  }
  float4 v = *(const float4*)src;
  bf16x4 o = { (bf16)v.x, (bf16)v.y, (bf16)v.z, (bf16)v.w };
  *(bf16x4*)(Wc + (size_t)r * KTOT + k4) = o;
}

__device__ __forceinline__ float sigm(float x) { return 1.f / (1.f + __expf(-x)); }
__device__ __forceinline__ float tanh_fast(float x) { return 2.f / (1.f + __expf(-2.f * x)) - 1.f; }

__device__ __forceinline__ u64 llc_load(const void* p) {
  return __hip_atomic_load((const u64*)p, __ATOMIC_RELAXED, __HIP_MEMORY_SCOPE_AGENT);
}

__global__ __launch_bounds__(256, 1) void k_lstm(
    const float* __restrict__ bih, const float* __restrict__ bhh,
    const bf16* __restrict__ xb, const bf16* __restrict__ Wc,
    bf16* __restrict__ h0, bf16* __restrict__ h1, unsigned* __restrict__ flags)
{
  __shared__ bf16  Wl[32 * WPITCH];   // 82,432 B
  __shared__ float gl[32][33];        // gates staging, +1 pad col
  __shared__ bf16  hstage[32][8];

  const int tid = threadIdx.x;
  const int wg  = blockIdx.x;
  const int ib  = wg & 1;      // batch half (32 rows)
  const int j   = wg >> 1;     // h block (8 h-cols), 0..127

  // ---- load weight slice into LDS (rows n = g*8+u -> global row g*1024 + j*8 + u)
  {
    const int n = tid >> 3;                       // 0..31
    const int g = n >> 3, u = n & 7;
    const bf16* srow = Wc + (size_t)(g * 1024 + j * 8 + u) * KTOT;
    bf16* drow = Wl + n * WPITCH;
    const int c0 = (tid & 7) * 8;
#pragma unroll
    for (int it = 0; it < 20; ++it) {
      int e = c0 + it * 64;                       // covers 0..1279
      *(bf16x8*)(drow + e) = *(const bf16x8*)(srow + e);
    }
  }

  const int lane = tid & 63;
  const int wv   = tid >> 6;         // 4 waves
  const int mt   = wv & 1;           // M-tile (16 batches)
  const int nt   = wv >> 1;          // N-tile (16 gate cols)
  const int ln   = lane & 15;
  const int hg   = lane >> 4;        // 0..3

  float bias_r;                      // per-lane: bias of gate col (nt*16+ln)
  {
    int nl = nt * 16 + ln;
    int g = nl >> 3, u = nl & 7;
    int r = g * 1024 + j * 8 + u;
    bias_r = bih[r] + bhh[r];
  }

  const int eb = tid & 31, eu = tid >> 5;   // epilogue ownership: (batch eb, hcol eu)
  float c_st = 0.f;                         // cell state, fp32 in register

  const int bg = ib * 32 + mt * 16 + ln;    // global batch row for A fragment
  const bf16* brow = Wl + (nt * 16 + ln) * WPITCH + hg * 8;

  unsigned* ownflag = flags + (size_t)wg * 16;

  __syncthreads();

  for (int t = 0; t < TSTEPS; ++t) {
    const bf16* hc = (t & 1) ? h1 : h0;     // read h_{t-1}
    bf16*       hn = (t & 1) ? h0 : h1;     // write h_t

    f32x4 acc = {0.f, 0.f, 0.f, 0.f};

    // ---- x-projection (xb immutable) hoisted ABOVE the barrier wait
    const bf16* ax = xb + (size_t)t * (BATCH * FEAT) + (size_t)bg * FEAT + hg * 8;
#pragma unroll
    for (int kc = 0; kc < 8; ++kc) {        // x part: K = 1024..1279
      bf16x8 a = *(const bf16x8*)(ax + kc * 32);
      bf16x8 b = *(const bf16x8*)(brow + 1024 + kc * 32);
      acc = __builtin_amdgcn_mfma_f32_16x16x32_bf16(a, b, acc, 0, 0, 0);
    }

    // ---- grid barrier wait: 64 threads poll 4 flags each (global wait set)
    if (t && tid < 64) {
#pragma unroll
      for (int q = 0; q < 4; ++q) {
        unsigned* pf = flags + (size_t)(tid + q * 64) * 16;
        while (__hip_atomic_load(pf, __ATOMIC_RELAXED, __HIP_MEMORY_SCOPE_AGENT) < (unsigned)t)
          __builtin_amdgcn_s_sleep(2);
      }
    }
    __syncthreads();

    // ---- h part: agent-scope atomic loads (coherence-point reads, fence-free)
    const bf16* ah = hc + (size_t)bg * HID + hg * 8;
#pragma unroll
    for (int kc = 0; kc < 32; ++kc) {       // h part: K = 0..1023
      u64 lo = llc_load(ah + kc * 32);
      u64 hi = llc_load(ah + kc * 32 + 4);
      bf16x4 l4 = __builtin_bit_cast(bf16x4, lo);
      bf16x4 h4 = __builtin_bit_cast(bf16x4, hi);
      bf16x8 a = { l4[0], l4[1], l4[2], l4[3], h4[0], h4[1], h4[2], h4[3] };
      bf16x8 b = *(const bf16x8*)(brow + kc * 32);
      acc = __builtin_amdgcn_mfma_f32_16x16x32_bf16(a, b, acc, 0, 0, 0);
    }

    // C/D layout (verified): col = lane&15, row = (lane>>4)*4 + reg
#pragma unroll
    for (int r = 0; r < 4; ++r)
      gl[mt * 16 + hg * 4 + r][nt * 16 + ln] = acc[r] + bias_r;
    __syncthreads();

    // ---- LSTM cell (each thread owns one (batch, hcol))
    float gi = gl[eb][ 0 + eu];
    float gf = gl[eb][ 8 + eu];
    float gc = gl[eb][16 + eu];
    float go = gl[eb][24 + eu];
    gi = sigm(gi); gf = sigm(gf); go = sigm(go); gc = tanh_fast(gc);
    c_st = gf * c_st + gi * gc;
    hstage[eb][eu] = (bf16)(go * tanh_fast(c_st));
    __syncthreads();

    // ---- publish h tile via atomicExch (commits at coherence point), then flag
    if (wv == 0) {
      u64 d0 = 0, d1 = 0;
      if (tid < 32) {
        const u64* hp = (const u64*)&hstage[tid][0];
        u64* dst = (u64*)(hn + (size_t)(ib * 32 + tid) * HID + j * 8);
        d0 = __hip_atomic_exchange(dst,     hp[0], __ATOMIC_RELAXED, __HIP_MEMORY_SCOPE_AGENT);
        d1 = __hip_atomic_exchange(dst + 1, hp[1], __ATOMIC_RELAXED, __HIP_MEMORY_SCOPE_AGENT);
      }
      asm volatile("" :: "v"(d0), "v"(d1));            // keep returns live (sc0 form)
      asm volatile("s_waitcnt vmcnt(0)" ::: "memory");  // h committed at MALL
      if (tid == 0)
        atomicExch(ownflag, (unsigned)(t + 1));
    }
  }
}

// out[b][c] = sum_k h_last[b][k] * Wfc[c][k]   (131 MFLOP, L2-resident)
__global__ __launch_bounds__(256) void k_fc(const bf16* __restrict__ h,
                                            const float* __restrict__ Wfc,
                                            float* __restrict__ out) {
  const int tid = threadIdx.x;
  const int ci = tid & 3, b = tid >> 2;
  const int c = blockIdx.x * 4 + ci;
  const bf16*  hr = h   + (size_t)b * HID;
  const float* wr = Wfc + (size_t)c * HID;
  float acc = 0.f;
#pragma unroll 4
  for (int k8 = 0; k8 < 128; ++k8) {
    bf16x8 hv = *(const bf16x8*)(hr + k8 * 8);
    f32x4  w0 = *(const f32x4*)(wr + k8 * 8);
    f32x4  w1 = *(const f32x4*)(wr + k8 * 8 + 4);
    acc += (float)hv[0] * w0[0] + (float)hv[1] * w0[1] + (float)hv[2] * w0[2] + (float)hv[3] * w0[3]
         + (float)hv[4] * w1[0] + (float)hv[5] * w1[1] + (float)hv[6] * w1[2] + (float)hv[7] * w1[3];
  }
  out[(size_t)b * 1000 + c] = acc;
}

extern "C" void kernel_launch(void* const* d_in, const int* in_sizes, int n_in,
                              void* d_out, int out_size, void* d_ws, size_t ws_size,
                              hipStream_t stream) {
  (void)in_sizes; (void)n_in; (void)out_size; (void)ws_size;
  const float* x   = (const float*)d_in[0];
  const float* Wih = (const float*)d_in[1];
  const float* Whh = (const float*)d_in[2];
  const float* bih = (const float*)d_in[3];
  const float* bhh = (const float*)d_in[4];
  const float* Wfc = (const float*)d_in[5];
  char* ws = (char*)d_ws;
  bf16* xb = (bf16*)(ws + WS_X);
  bf16* Wc = (bf16*)(ws + WS_W);
  bf16* h0 = (bf16*)(ws + WS_H0);
  bf16* h1 = (bf16*)(ws + WS_H1);
  unsigned* flags = (unsigned*)(ws + WS_FLG);

  hipLaunchKernelGGL(k_zero,    dim3(68),      dim3(256), 0, stream, (uint4*)(ws + WS_H0));
  hipLaunchKernelGGL(k_conv_x,  dim3(8192),    dim3(256), 0, stream, x, xb);
  hipLaunchKernelGGL(k_build_w, dim3(4096, 2), dim3(256), 0, stream, Wih, Whh, Wc);
  hipLaunchKernelGGL(k_lstm,    dim3(NWG),     dim3(256), 0, stream, bih, bhh, xb, Wc, h0, h1, flags);
  hipLaunchKernelGGL(k_fc,      dim3(250),     dim3(256), 0, stream, h0, Wfc, (float*)d_out);
}